// Round 7
// baseline (492.928 us; speedup 1.0000x reference)
//
#include <hip/hip_runtime.h>

typedef unsigned short u16;
typedef unsigned int   u32;
typedef __attribute__((ext_vector_type(8))) short bf16x8;   // 8 bf16 = 4 VGPRs
typedef __attribute__((ext_vector_type(4))) float f32x4;

#define S_LEN 2048
#define B_SZ  2
#define H_DIM 2048
#define NH_   16
#define HN_   128
#define M_TOK 4096          /* tokens, row = s*B + b */
#define NQKV  6144

// raw barrier: does NOT drain vmcnt -- staged loads stay in flight across it
#define BAR      asm volatile("s_barrier" ::: "memory")
#define WAITV(n) asm volatile("s_waitcnt vmcnt(" #n ")" ::: "memory")
// barrier that drains LDS ops only (ds-read WAR safety) -- never vmcnt
#define LGKM_BAR asm volatile("s_waitcnt lgkmcnt(0)\n\ts_barrier" ::: "memory")

// float -> bf16 round-to-nearest-even
__device__ __forceinline__ u16 f2bf(float f) {
    u32 x = __float_as_uint(f);
    return (u16)((x + 0x7fffu + ((x >> 16) & 1u)) >> 16);
}

// async global->LDS, 16 B per lane
__device__ __forceinline__ void async16(const void* g, void* l) {
    __builtin_amdgcn_global_load_lds((const __attribute__((address_space(1))) void*)g,
                                     (__attribute__((address_space(3))) void*)l,
                                     16, 0, 0);
}

// one launch converting all three fp32 tensors to bf16 (each size % 4 == 0)
__global__ __launch_bounds__(256) void cvt3(
    const float* __restrict__ a, u16* __restrict__ oa, int na,   // float4-groups
    const float* __restrict__ b, u16* __restrict__ ob, int nb,
    const float* __restrict__ c, u16* __restrict__ oc, int nc)
{
    int g = blockIdx.x * 256 + threadIdx.x;
    const float* in; u16* out; int idx;
    if (g < na)           { in = a; out = oa; idx = g; }
    else if (g < na + nb) { in = b; out = ob; idx = g - na; }
    else if (g < na + nb + nc) { in = c; out = oc; idx = g - na - nb; }
    else return;
    int i = idx * 4;
    float4 v = *(const float4*)&in[i];
    ushort4 o;
    o.x = f2bf(v.x); o.y = f2bf(v.y); o.z = f2bf(v.z); o.w = f2bf(v.w);
    *(ushort4*)&out[i] = o;
}

// ---------------------------------------------------------------------------
// 256x256 8-phase bf16 GEMM (R5 hoisted-read schedule, unchanged -- best so
// far: 142 us QKV). See R5 notes: per phase {STAGE Xi; MFMA(q); next reads;
// BAR}, WAITV(4) at ph3/ph7, snake quadrants, T2 source-side swizzle.
// ---------------------------------------------------------------------------
template<int EPI, int MM, int NN>
__global__ __launch_bounds__(512, 2) void gemm8(
    const u16* __restrict__ A, const u16* __restrict__ W,
    const float* __restrict__ bias, float* __restrict__ Cout,
    u16* __restrict__ Qb, u16* __restrict__ Kb, u16* __restrict__ Vt)
{
    constexpr int K   = 2048;
    constexpr int NKT = K / 64;            // 32 K-tiles
    constexpr int NBN = NN / 256;
    constexpr int NWG = (MM / 256) * NBN;  // % 8 == 0 for all our shapes

    __shared__ __align__(16) u16 sA[2][256 * 64];   // 2 x 32 KB
    __shared__ __align__(16) u16 sB[2][256 * 64];   // 2 x 32 KB

    const int t = threadIdx.x, l = t & 63, w = t >> 6;
    const int quad = l >> 4, ln = l & 15;
    const int qw_r = w >> 2, qw_c = w & 3;   // wave grid 2x4 inside a quadrant

    int wg = blockIdx.x;
    wg = (wg & 7) * (NWG / 8) + (wg >> 3);   // bijective XCD swizzle (NWG%8==0)
    const int m0 = (wg / NBN) * 256, n0 = (wg % NBN) * 256;

    const int srow = t >> 3;                          // 0..63 (chunk c=t)
    const int skc  = (t & 7) ^ (srow & 7);            // swizzled k-chunk
    const u16* pA = A + (size_t)(m0 + srow) * K + skc * 8;
    const u16* pB = W + (size_t)(n0 + srow) * K + skc * 8;

#define STAGE_A(db, h, kt)                                                        \
    do {                                                                          \
        async16(pA + (size_t)(h) * 128 * K + (size_t)(kt) * 64,                   \
                &sA[db][(h) * 8192 + t * 8]);                                     \
        async16(pA + (size_t)(h) * 128 * K + (size_t)64 * K + (size_t)(kt) * 64,  \
                &sA[db][(h) * 8192 + t * 8 + 4096]);                              \
    } while (0)
#define STAGE_B(db, h, kt)                                                        \
    do {                                                                          \
        async16(pB + (size_t)(h) * 128 * K + (size_t)(kt) * 64,                   \
                &sB[db][(h) * 8192 + t * 8]);                                     \
        async16(pB + (size_t)(h) * 128 * K + (size_t)64 * K + (size_t)(kt) * 64,  \
                &sB[db][(h) * 8192 + t * 8 + 4096]);                              \
    } while (0)

    const int aBase = (qw_r * 64 + ln) * 64;
    const int bBase = (qw_c * 32 + ln) * 64;
    int swz[2];
#pragma unroll
    for (int ks = 0; ks < 2; ++ks)
        swz[ks] = ((ks * 4 + quad) ^ (ln & 7)) << 3;

    bf16x8 af[4][2];    // A frags (holds h0 or h1; overwritten after last use)
    bf16x8 bS0[2][2];   // B n-half-0 frags
    bf16x8 bS1[2][2];   // B n-half-1 frags

#define RD_A(db, mq)                                                              \
    do {                                                                          \
        _Pragma("unroll") for (int mf = 0; mf < 4; ++mf)                          \
        _Pragma("unroll") for (int ks = 0; ks < 2; ++ks)                          \
            af[mf][ks] = *(const bf16x8*)&sA[db][aBase + (mq) * 8192 + mf * 1024  \
                                                + swz[ks]];                       \
    } while (0)
#define RD_B(db, nq, SET)                                                         \
    do {                                                                          \
        _Pragma("unroll") for (int nf = 0; nf < 2; ++nf)                          \
        _Pragma("unroll") for (int ks = 0; ks < 2; ++ks)                          \
            SET[nf][ks] = *(const bf16x8*)&sB[db][bBase + (nq) * 8192 + nf * 1024 \
                                                 + swz[ks]];                      \
    } while (0)

    f32x4 acc[4][4][2];   // [quadrant mq*2+nq][m-frag][n-frag]
#pragma unroll
    for (int q = 0; q < 4; ++q)
#pragma unroll
        for (int mf = 0; mf < 4; ++mf)
#pragma unroll
            for (int nf = 0; nf < 2; ++nf)
#pragma unroll
                for (int r = 0; r < 4; ++r) acc[q][mf][nf][r] = 0.f;

#define MM16(q, SET)                                                              \
    do {                                                                          \
        __builtin_amdgcn_s_setprio(1);                                            \
        _Pragma("unroll") for (int mf = 0; mf < 4; ++mf)                          \
        _Pragma("unroll") for (int nf = 0; nf < 2; ++nf)                          \
        _Pragma("unroll") for (int ks = 0; ks < 2; ++ks)                          \
            acc[q][mf][nf] = __builtin_amdgcn_mfma_f32_16x16x32_bf16(             \
                af[mf][ks], SET[nf][ks], acc[q][mf][nf], 0, 0, 0);                \
        __builtin_amdgcn_s_setprio(0);                                            \
    } while (0)

    // ---- prologue: T0 fully + T1's A0,B0,B1; force T0 (leave 6); first S1
    STAGE_A(0, 0, 0); STAGE_B(0, 0, 0); STAGE_B(0, 1, 0); STAGE_A(0, 1, 0);
    STAGE_A(1, 0, 1); STAGE_B(1, 0, 1); STAGE_B(1, 1, 1);
    WAITV(6);
    BAR;
    RD_A(0, 0); RD_B(0, 0, bS0);            // S1 for first ph1 (exposed once)

#pragma unroll 1
    for (int i = 0; i < NKT / 2; ++i) {
        const int tt  = 2 * i;
        const int tp1 = tt + 1;                 // never wraps (tt <= 30)
        const int tp2 = (tt + 2) & (NKT - 1);   // wraps to dummy refill at end
        const int tp3 = (tt + 3) & (NKT - 1);

        // ph1: q(0,0) tile t buf0  [af=h0, bS0 from prev ph8 / prologue]
        STAGE_A(1, 1, tp1);                 // X1: buf1-Ah1 (readers done prev ph7)
        MM16(0, bS0);
        RD_B(0, 1, bS1);                    // S2 -> ph2
        BAR;
        // ph2: q(0,1)
        STAGE_A(0, 0, tp2);                 // X2: buf0-Ah0 (read by prev S1'' <= ph1)
        MM16(1, bS1);
        RD_A(0, 1);                         // S3: af -> h1, for ph3+ph4
        BAR;
        // ph3: q(1,1)
        STAGE_B(0, 0, tp2);                 // X3: buf0-Bh0 (read by prev S1'' <= ph1)
        MM16(3, bS1);
        WAITV(4);                           // forces tile t+1's 4 halves
        BAR;
        // ph4: q(1,0)  [af=h1, bS0 still tile t]
        STAGE_B(0, 1, tp2);                 // X4: buf0-Bh1 (read by S2 <= ph2)
        MM16(2, bS0);
        RD_A(1, 0); RD_B(1, 0, bS0);        // S1': buf1 tile t+1 (forced @ph3)
        BAR;
        // ph5: q(0,0) tile t+1 buf1
        STAGE_A(0, 1, tp2);                 // X5: buf0-Ah1 (read by S3 <= ph3)
        MM16(0, bS0);
        RD_B(1, 1, bS1);                    // S2'
        BAR;
        // ph6: q(0,1)
        STAGE_A(1, 0, tp3);                 // X6: buf1-Ah0 (read by S1' <= ph5)
        MM16(1, bS1);
        RD_A(1, 1);                         // S3'
        BAR;
        // ph7: q(1,1)
        STAGE_B(1, 0, tp3);                 // X7: buf1-Bh0 (read by S1' <= ph5)
        MM16(3, bS1);
        WAITV(4);                           // forces tile t+2's 4 halves
        BAR;
        // ph8: q(1,0)
        STAGE_B(1, 1, tp3);                 // X8: buf1-Bh1 (read by S2' <= ph6)
        MM16(2, bS0);
        RD_A(0, 0); RD_B(0, 0, bS0);        // S1'': buf0 tile t+2 (forced @ph7)
        BAR;
    }
#undef STAGE_A
#undef STAGE_B
#undef RD_A
#undef RD_B
#undef MM16

    // C/D layout: col = lane&15, row = (lane>>4)*4 + reg   [verified m89/m91]
    if constexpr (EPI == 0) {
#pragma unroll
        for (int q = 0; q < 4; ++q) {
            const int mq = q >> 1, nq = q & 1;
#pragma unroll
            for (int mf = 0; mf < 4; ++mf)
#pragma unroll
                for (int nf = 0; nf < 2; ++nf) {
                    int col = n0 + nq * 128 + qw_c * 32 + nf * 16 + ln;
#pragma unroll
                    for (int r = 0; r < 4; ++r) {
                        int row = m0 + mq * 128 + qw_r * 64 + mf * 16 + quad * 4 + r;
                        Cout[(size_t)row * NN + col] = acc[q][mf][nf][r];
                    }
                }
        }
    } else {
        // fold 1/sqrt(128) * log2(e) into Q so softmax uses exp2
        const float kQS = 0.08838834764831845f * 1.44269504088896340f;
#pragma unroll
        for (int q = 0; q < 4; ++q) {
            const int mq = q >> 1, nq = q & 1;
#pragma unroll
            for (int nf = 0; nf < 2; ++nf) {
                int col  = n0 + nq * 128 + qw_c * 32 + nf * 16 + ln;
                int head = col / 384;
                int g    = col - head * 384;
                int sec  = g >> 7;        // 0=q 1=k 2=v (uniform over 16-span)
                int d    = g & 127;
                float bv = bias[col];
#pragma unroll
                for (int mf = 0; mf < 4; ++mf)
#pragma unroll
                    for (int r = 0; r < 4; ++r) {
                        int tok = m0 + mq * 128 + qw_r * 64 + mf * 16 + quad * 4 + r;
                        int s = tok >> 1, bb = tok & 1;
                        float v = acc[q][mf][nf][r] + bv;
                        if (sec == 0)
                            Qb[((size_t)(bb * NH_ + head) * S_LEN + s) * HN_ + d] = f2bf(v * kQS);
                        else if (sec == 1)
                            Kb[((size_t)(bb * NH_ + head) * S_LEN + s) * HN_ + d] = f2bf(v);
                        else  // V stored transposed [d][s] for PV B-fragments
                            Vt[((size_t)(bb * NH_ + head) * HN_ + d) * S_LEN + s] = f2bf(v);
                    }
            }
        }
    }
}

// ---------------------------------------------------------------------------
// MFMA flash attention R6: QBLK=128 (4 waves x 32 q-rows) -- each K/V LDS
// fragment now feeds TWO MFMAs (was one), halving per-q-row LDS-read cost
// (the measured 3264-cyc dominant term). K double-buffered, V SINGLE-buffered
// (LDS 32+16+16 = 64 KB -> 2 blocks/CU). Q loaded global->regs (32 VGPR).
// Raw lgkm-only barriers everywhere: __syncthreads would drain vmcnt and
// kill the K/V prefetch. vmcnt ledger (hand-walked, uniform all iters):
//   top:  outstanding = K(kt)4 [oldest] + V(kt)4 -> WAITV(4) drains K(kt)
//   mid:  outstanding = V(kt)4 [oldest] + K(kt+1)4 -> WAITV(4) drains V(kt)
//         (last iter: no K issued -> WAITV(0))
//   post-PV: LGKM_BAR then issue V(kt+1) (WAR: all waves' vf reads retired)
// Psm[4][32][64] chunk-swizzled: chunk ^= (row^(row>>3))&7 -- write/read
// consistent, pf b128 reads 2-way (free), fits without the +8 pad.
// Block j does Q-tiles {15-j, j}: uniform 36 kt-iters; grid 8x16x2 = 256
// blocks x 2/CU = full GPU.
// ---------------------------------------------------------------------------
__global__ __launch_bounds__(256, 2) void attn_mfma(
    const u16* __restrict__ Qb, const u16* __restrict__ Kb,
    const u16* __restrict__ Vt, u16* __restrict__ Ctx)
{
    __shared__ __align__(16) u16 Ks[2][16 * 64 * 8];   // 2 x 16 KB (64 tok x 128 d)
    __shared__ __align__(16) u16 Vs[16 * 64 * 8];      // 16 KB (128 d x 64 tok)
    __shared__ __align__(16) u16 Psm[4 * 32 * 64];     // 16 KB, swizzled chunks

    const int t = threadIdx.x, l = t & 63, w = t >> 6;
    const int quad = l >> 4, ln = l & 15;
    const int j = blockIdx.x;       // 0..7
    const int n = blockIdx.y, b = blockIdx.z;
    const u16* Qh = Qb + (size_t)(b * NH_ + n) * S_LEN * HN_;
    const u16* Kh = Kb + (size_t)(b * NH_ + n) * S_LEN * HN_;
    const u16* Vh = Vt + (size_t)(b * NH_ + n) * HN_ * S_LEN;
    u16* Pw = &Psm[w * 2048];

#define STAGE_K(buf, kt)                                                           \
    do { _Pragma("unroll") for (int i = 0; i < 4; ++i)                             \
        async16(&Kh[(size_t)((kt) * 64 + i * 16 + ln) * HN_ + w * 32 + quad * 8],  \
                &Ks[buf][((i * 4 + w) * 64 + l) * 8]); } while (0)
#define STAGE_V(kt)                                                               \
    do { _Pragma("unroll") for (int i = 0; i < 4; ++i) {                          \
        int dv = i * 4 + w, dvt = dv >> 1, ks = dv & 1;                           \
        async16(&Vh[(size_t)(dvt * 16 + ln) * S_LEN + (kt) * 64 + ks * 32 + quad * 8], \
                &Vs[(dv * 64 + l) * 8]); } } while (0)

#pragma unroll 1
    for (int phase = 0; phase < 2; ++phase) {
        const int qt  = phase ? j : (15 - j);
        const int q0  = qt * 128;
        const int nkt = 2 * qt + 2;

        // Q -> registers (A-frag layout: lane row l&15, k-cols (l>>4)*8)
        bf16x8 qf[2][4];
#pragma unroll
        for (int mf = 0; mf < 2; ++mf)
#pragma unroll
            for (int ks = 0; ks < 4; ++ks)
                qf[mf][ks] = *(const bf16x8*)
                    &Qh[(size_t)(q0 + w * 32 + mf * 16 + ln) * HN_ + ks * 32 + quad * 8];

        LGKM_BAR;               // prior-phase LDS reads retired before overwrite
        STAGE_K(0, 0);
        STAGE_V(0);

        float m_i[2][4], l_i[2][4];
        f32x4 acco[2][8];
#pragma unroll
        for (int mf = 0; mf < 2; ++mf)
#pragma unroll
            for (int r = 0; r < 4; ++r) { m_i[mf][r] = -1e30f; l_i[mf][r] = 0.f; }
#pragma unroll
        for (int mf = 0; mf < 2; ++mf)
#pragma unroll
            for (int dt = 0; dt < 8; ++dt)
#pragma unroll
                for (int r = 0; r < 4; ++r) acco[mf][dt][r] = 0.f;

#pragma unroll 1
        for (int kt = 0; kt < nkt; ++kt) {
            const int cur = kt & 1;
            const bool last = (kt == nkt - 1);

            WAITV(4);           // drain K(kt) (oldest 4; V(kt) stays in flight)
            LGKM_BAR;           // K(kt) visible to all waves
            if (!last) STAGE_K(cur ^ 1, kt + 1);

            // S = Q K^T : 32 q-rows x 64 k-tokens per wave (each kf feeds 2 MFMA)
            f32x4 sc[2][4];
#pragma unroll
            for (int mf = 0; mf < 2; ++mf)
#pragma unroll
                for (int nt = 0; nt < 4; ++nt)
#pragma unroll
                    for (int r = 0; r < 4; ++r) sc[mf][nt][r] = 0.f;
#pragma unroll
            for (int nt = 0; nt < 4; ++nt)
#pragma unroll
                for (int ks = 0; ks < 4; ++ks) {
                    bf16x8 kf = *(const bf16x8*)&Ks[cur][((nt * 4 + ks) * 64 + l) * 8];
#pragma unroll
                    for (int mf = 0; mf < 2; ++mf)
                        sc[mf][nt] = __builtin_amdgcn_mfma_f32_16x16x32_bf16(
                            qf[mf][ks], kf, sc[mf][nt], 0, 0, 0);
                }

            if (kt >= 2 * qt) {   // diagonal 64-col band(s)
#pragma unroll
                for (int mf = 0; mf < 2; ++mf)
#pragma unroll
                    for (int nt = 0; nt < 4; ++nt)
#pragma unroll
                        for (int r = 0; r < 4; ++r)
                            if ((kt - 2 * qt) * 64 + nt * 16 + ln >
                                w * 32 + mf * 16 + quad * 4 + r)
                                sc[mf][nt][r] = -1e30f;
            }

            // online softmax (base-2; scale folded into Q)
            float corr[2][4];
#pragma unroll
            for (int mf = 0; mf < 2; ++mf)
#pragma unroll
                for (int r = 0; r < 4; ++r) {
                    float mx = fmaxf(fmaxf(sc[mf][0][r], sc[mf][1][r]),
                                     fmaxf(sc[mf][2][r], sc[mf][3][r]));
                    mx = fmaxf(mx, __shfl_xor(mx, 1));
                    mx = fmaxf(mx, __shfl_xor(mx, 2));
                    mx = fmaxf(mx, __shfl_xor(mx, 4));
                    mx = fmaxf(mx, __shfl_xor(mx, 8));
                    float mnew = fmaxf(m_i[mf][r], mx);
                    corr[mf][r] = exp2f(m_i[mf][r] - mnew);
                    m_i[mf][r] = mnew;
                }
#pragma unroll
            for (int mf = 0; mf < 2; ++mf)
#pragma unroll
                for (int r = 0; r < 4; ++r) {
                    float ps = 0.f;
                    const int row = mf * 16 + quad * 4 + r;
                    const int sw = (row ^ (row >> 3)) & 7;
#pragma unroll
                    for (int nt = 0; nt < 4; ++nt) {
                        float p = exp2f(sc[mf][nt][r] - m_i[mf][r]);
                        ps += p;
                        Pw[row * 64 + (((nt * 2 + (ln >> 3)) ^ sw) << 3) + (ln & 7)] = f2bf(p);
                    }
                    l_i[mf][r] = l_i[mf][r] * corr[mf][r] + ps;
                }
#pragma unroll
            for (int mf = 0; mf < 2; ++mf)
#pragma unroll
                for (int dt = 0; dt < 8; ++dt)
#pragma unroll
                    for (int r = 0; r < 4; ++r) acco[mf][dt][r] *= corr[mf][r];

            // V(kt) arrival (oldest 4; last iter has nothing newer in flight)
            if (!last) { WAITV(4); } else { WAITV(0); }
            LGKM_BAR;           // V(kt) visible; own Psm writes drained (lgkm)

            // O += P @ V  (each vf feeds 2 MFMA)
            bf16x8 pf[2][2];
#pragma unroll
            for (int mf = 0; mf < 2; ++mf)
#pragma unroll
                for (int ks = 0; ks < 2; ++ks) {
                    const int row = mf * 16 + ln;
                    const int sw = (row ^ (row >> 3)) & 7;
                    pf[mf][ks] = *(const bf16x8*)
                        &Pw[row * 64 + (((ks * 4 + quad) ^ sw) << 3)];
                }
#pragma unroll
            for (int dt = 0; dt < 8; ++dt)
#pragma unroll
                for (int ks = 0; ks < 2; ++ks) {
                    bf16x8 vf = *(const bf16x8*)&Vs[((dt * 2 + ks) * 64 + l) * 8];
#pragma unroll
                    for (int mf = 0; mf < 2; ++mf)
                        acco[mf][dt] = __builtin_amdgcn_mfma_f32_16x16x32_bf16(
                            pf[mf][ks], vf, acco[mf][dt], 0, 0, 0);
                }

            if (!last) {
                LGKM_BAR;       // all waves' vf reads retired -> Vs reusable
                STAGE_V(kt + 1);
            }
        }

        // finalize: reduce lane-partial l over the 16-lane group
#pragma unroll
        for (int mf = 0; mf < 2; ++mf)
#pragma unroll
            for (int r = 0; r < 4; ++r) {
                float s = l_i[mf][r];
                s += __shfl_xor(s, 1);
                s += __shfl_xor(s, 2);
                s += __shfl_xor(s, 4);
                s += __shfl_xor(s, 8);
                l_i[mf][r] = 1.f / s;
            }
#pragma unroll
        for (int mf = 0; mf < 2; ++mf)
#pragma unroll
            for (int dt = 0; dt < 8; ++dt)
#pragma unroll
                for (int r = 0; r < 4; ++r) {
                    int srow = q0 + w * 32 + mf * 16 + quad * 4 + r;
                    Ctx[((size_t)(srow * B_SZ + b)) * H_DIM + n * HN_ + dt * 16 + ln] =
                        f2bf(acco[mf][dt][r] * l_i[mf][r]);
                }
    }
#undef STAGE_K
#undef STAGE_V
}

__global__ void copy_bias(const float* __restrict__ b_dense, float* __restrict__ out)
{
    int t = blockIdx.x * 256 + threadIdx.x;
    if (t < H_DIM) out[(size_t)M_TOK * H_DIM + t] = b_dense[t];
}

extern "C" void kernel_launch(void* const* d_in, const int* in_sizes, int n_in,
                              void* d_out, int out_size, void* d_ws, size_t ws_size,
                              hipStream_t stream)
{
    const float* hs      = (const float*)d_in[0];
    /* d_in[1] attention_mask: compile-time causal, ignored */
    const float* w_qkv   = (const float*)d_in[2];
    const float* b_qkv   = (const float*)d_in[3];
    const float* w_dense = (const float*)d_in[4];
    const float* b_dense = (const float*)d_in[5];
    float* out = (float*)d_out;

    u16* hs_bf = (u16*)d_ws;                           //  16.8 MB
    u16* wq_bf = hs_bf + (size_t)M_TOK * H_DIM;        //  25.2 MB
    u16* wd_bf = wq_bf + (size_t)NQKV * H_DIM;         //   8.4 MB
    u16* Qb    = wd_bf + (size_t)H_DIM * H_DIM;        //  16.8 MB  [b][n][s][d]
    u16* Kb    = Qb    + (size_t)M_TOK * H_DIM;        //  16.8 MB  [b][n][s][d]
    u16* Vt    = Kb    + (size_t)M_TOK * H_DIM;        //  16.8 MB  [b][n][d][s]
    u16* Ctx   = Vt    + (size_t)M_TOK * H_DIM;        //  16.8 MB  [s][b][h]

    const int g1 = (M_TOK * H_DIM) / 4;   // float4-groups per tensor
    const int g2 = (NQKV * H_DIM) / 4;
    const int g3 = (H_DIM * H_DIM) / 4;
    cvt3<<<(g1 + g2 + g3 + 255) / 256, 256, 0, stream>>>(
        hs, hs_bf, g1, w_qkv, wq_bf, g2, w_dense, wd_bf, g3);

    gemm8<1, M_TOK, NQKV><<<(M_TOK / 256) * (NQKV / 256), 512, 0, stream>>>(
        hs_bf, wq_bf, b_qkv, nullptr, Qb, Kb, Vt);

    attn_mfma<<<dim3(8, NH_, B_SZ), 256, 0, stream>>>(Qb, Kb, Vt, Ctx);

    gemm8<0, M_TOK, H_DIM><<<(M_TOK / 256) * (H_DIM / 256), 512, 0, stream>>>(
        Ctx, wd_bf, nullptr, out, nullptr, nullptr, nullptr);

    copy_bias<<<(H_DIM + 255) / 256, 256, 0, stream>>>(b_dense, out);
}